// Round 1
// baseline (739.815 us; speedup 1.0000x reference)
//
#include <hip/hip_runtime.h>

#define LL 4096
#define HH 1024
#define PP 512
#define RR 16

__device__ __forceinline__ void ld4(const float* p, float v[4]) {
  float4 t = *(const float4*)p;
  v[0] = t.x; v[1] = t.y; v[2] = t.z; v[3] = t.w;
}
__device__ __forceinline__ void st4(float* p, const float v[4]) {
  float4 t; t.x = v[0]; t.y = v[1]; t.z = v[2]; t.w = v[3];
  *(float4*)p = t;
}

// ---------------------------------------------------------------- kernel 1
// per-p scalars: Lambda_bar = exp(Lam*step), coef = (Lambda_bar-1)/Lam,
// EF[r][p] = E[p][r]*F[r][p]
__global__ void precompute_kernel(const float* __restrict__ Lre, const float* __restrict__ Lim,
                                  const float* __restrict__ lst,
                                  const float* __restrict__ Ere, const float* __restrict__ Eim,
                                  const float* __restrict__ Fre, const float* __restrict__ Fim,
                                  float* __restrict__ Lbr, float* __restrict__ Lbi,
                                  float* __restrict__ cfr, float* __restrict__ cfi,
                                  float* __restrict__ EFr, float* __restrict__ EFi)
{
  int p = blockIdx.x * blockDim.x + threadIdx.x;
  if (p >= PP) return;
  float lre = fminf(Lre[p], -1e-4f);   // clip_eigs
  float lim = Lim[p];
  float st  = expf(lst[p]);
  float er  = expf(lre * st);
  float s, c;
  sincosf(lim * st, &s, &c);
  float lbr = er * c, lbi = er * s;    // Lambda_bar
  Lbr[p] = lbr; Lbi[p] = lbi;
  float den = lre * lre + lim * lim;
  float nr  = lbr - 1.0f;
  cfr[p] = (nr * lre + lbi * lim) / den;
  cfi[p] = (lbi * lre - nr * lim) / den;
  for (int r = 0; r < RR; ++r) {
    float e_r = Ere[p * RR + r], e_i = Eim[p * RR + r];
    float f_r = Fre[r * PP + p], f_i = Fim[r * PP + p];
    EFr[r * PP + p] = e_r * f_r - e_i * f_i;
    EFi[r * PP + p] = e_r * f_i + e_i * f_r;
  }
}

// ---------------------------------------------------------------- kernel 2
// B_bar[p][h] = coef[p] * (B_re + i B_im)[p][h]
__global__ void bbar_kernel(const float* __restrict__ Bre, const float* __restrict__ Bim,
                            const float* __restrict__ cfr, const float* __restrict__ cfi,
                            float* __restrict__ Bbr, float* __restrict__ Bbi)
{
  int i = blockIdx.x * blockDim.x + threadIdx.x;
  int base = i * 4;
  if (base >= PP * HH) return;
  int p = base >> 10;                  // H = 1024
  float cr = cfr[p], ci = cfi[p];
  float4 br = *(const float4*)&Bre[base];
  float4 bi = *(const float4*)&Bim[base];
  float4 orr, oii;
  orr.x = cr * br.x - ci * bi.x;  oii.x = cr * bi.x + ci * br.x;
  orr.y = cr * br.y - ci * bi.y;  oii.y = cr * bi.y + ci * br.y;
  orr.z = cr * br.z - ci * bi.z;  oii.z = cr * bi.z + ci * br.z;
  orr.w = cr * br.w - ci * bi.w;  oii.w = cr * bi.w + ci * br.w;
  *(float4*)&Bbr[base] = orr;
  *(float4*)&Bbi[base] = oii;
}

// ---------------------------------------------------------------- kernel 3
// Bu[l][p] = sum_h u[l][h]*B_bar[p][h]   (complex out, real u)
// Lam_el[l][p] = Lambda_bar[p] + sum_r Delta[l][r]*EF[r][p]
// 64x64 block tile, 256 threads, 4x4 per thread, fp32 vector.
__global__ __launch_bounds__(256) void gemm1_kernel(
    const float* __restrict__ U,  const float* __restrict__ Bbr, const float* __restrict__ Bbi,
    const float* __restrict__ Dt, const float* __restrict__ EFr, const float* __restrict__ EFi,
    const float* __restrict__ Lbr, const float* __restrict__ Lbi,
    float* __restrict__ Bur, float* __restrict__ Bui,
    float* __restrict__ Ler, float* __restrict__ Lei)
{
  __shared__ float As[16][68], Bsr[16][68], Bsi[16][68];
  int t  = threadIdx.x;
  int p0 = blockIdx.x * 64, l0 = blockIdx.y * 64;
  int tx = t & 15, ty = t >> 4;
  int lm = t >> 2, kq = (t & 3) * 4;
  float accr[4][4] = {}, acci[4][4] = {};

  for (int k0 = 0; k0 < HH; k0 += 16) {
    float4 av  = *(const float4*)&U  [(size_t)(l0 + lm) * HH + k0 + kq];
    float4 brv = *(const float4*)&Bbr[(size_t)(p0 + lm) * HH + k0 + kq];
    float4 biv = *(const float4*)&Bbi[(size_t)(p0 + lm) * HH + k0 + kq];
    __syncthreads();
    As [kq + 0][lm] = av.x;  As [kq + 1][lm] = av.y;  As [kq + 2][lm] = av.z;  As [kq + 3][lm] = av.w;
    Bsr[kq + 0][lm] = brv.x; Bsr[kq + 1][lm] = brv.y; Bsr[kq + 2][lm] = brv.z; Bsr[kq + 3][lm] = brv.w;
    Bsi[kq + 0][lm] = biv.x; Bsi[kq + 1][lm] = biv.y; Bsi[kq + 2][lm] = biv.z; Bsi[kq + 3][lm] = biv.w;
    __syncthreads();
#pragma unroll
    for (int k = 0; k < 16; ++k) {
      float a[4], br[4], bi[4];
      ld4(&As[k][ty * 4], a);
      ld4(&Bsr[k][tx * 4], br);
      ld4(&Bsi[k][tx * 4], bi);
#pragma unroll
      for (int j = 0; j < 4; ++j)
#pragma unroll
        for (int i = 0; i < 4; ++i) {
          accr[j][i] = fmaf(a[j], br[i], accr[j][i]);
          acci[j][i] = fmaf(a[j], bi[i], acci[j][i]);
        }
    }
  }

  // ---- ext = Delta @ EF  (K = 16), reuse LDS
  __syncthreads();
  {
    float4 dv = *(const float4*)&Dt[(size_t)(l0 + lm) * RR + kq];
    As[kq + 0][lm] = dv.x; As[kq + 1][lm] = dv.y; As[kq + 2][lm] = dv.z; As[kq + 3][lm] = dv.w;
    int r = t >> 4, nq = (t & 15) * 4;
    float4 efr = *(const float4*)&EFr[r * PP + p0 + nq];
    float4 efi = *(const float4*)&EFi[r * PP + p0 + nq];
    *(float4*)&Bsr[r][nq] = efr;
    *(float4*)&Bsi[r][nq] = efi;
  }
  __syncthreads();
  float extr[4][4] = {}, exti[4][4] = {};
#pragma unroll
  for (int r = 0; r < 16; ++r) {
    float d[4], er[4], ei[4];
    ld4(&As[r][ty * 4], d);
    ld4(&Bsr[r][tx * 4], er);
    ld4(&Bsi[r][tx * 4], ei);
#pragma unroll
    for (int j = 0; j < 4; ++j)
#pragma unroll
      for (int i = 0; i < 4; ++i) {
        extr[j][i] = fmaf(d[j], er[i], extr[j][i]);
        exti[j][i] = fmaf(d[j], ei[i], exti[j][i]);
      }
  }
  float lbr4[4], lbi4[4];
  ld4(&Lbr[p0 + tx * 4], lbr4);
  ld4(&Lbi[p0 + tx * 4], lbi4);
#pragma unroll
  for (int j = 0; j < 4; ++j) {
    int row = l0 + ty * 4 + j;
    size_t b = (size_t)row * PP + p0 + tx * 4;
    st4(&Bur[b], accr[j]);
    st4(&Bui[b], acci[j]);
    float le_r[4], le_i[4];
#pragma unroll
    for (int i = 0; i < 4; ++i) { le_r[i] = extr[j][i] + lbr4[i]; le_i[i] = exti[j][i] + lbi4[i]; }
    st4(&Ler[b], le_r);
    st4(&Lei[b], le_i);
  }
}

// ---------------------------------------------------------------- kernel 4
// fwd/bwd diagonal complex scans: x[l] = A[l]*x[l-1] + b[l]
// one thread per (p, direction); register double-buffer prefetch of 8 steps.
__global__ __launch_bounds__(256) void scan_kernel(
    const float* __restrict__ Aer, const float* __restrict__ Aei,
    const float* __restrict__ Bur, const float* __restrict__ Bui,
    float* __restrict__ xfr, float* __restrict__ xfi,
    float* __restrict__ xbr, float* __restrict__ xbi)
{
  int t = blockIdx.x * blockDim.x + threadIdx.x;   // 0..1023
  int p = t & (PP - 1);
  int bwd = t >> 9;                                 // 0 fwd, 1 bwd (wave-uniform)
  float* __restrict__ outr = bwd ? xbr : xfr;
  float* __restrict__ outi = bwd ? xbi : xfi;
  float xr = 0.f, xi = 0.f;
  const int NC = LL / 8;                            // 512 chunks

  float a0r[8], a0i[8], b0r[8], b0i[8];
  float a1r[8], a1i[8], b1r[8], b1i[8];

#define LOADC(ar_, ai_, br_, bi_, c_) do {                                   \
    _Pragma("unroll")                                                        \
    for (int u = 0; u < 8; ++u) {                                            \
      int l = (c_) * 8 + u;                                                  \
      int phys = bwd ? (LL - 1 - l) : l;                                     \
      int idx = phys * PP + p;                                               \
      ar_[u] = Aer[idx]; ai_[u] = Aei[idx];                                  \
      br_[u] = Bur[idx]; bi_[u] = Bui[idx];                                  \
    } } while (0)

#define COMPC(ar_, ai_, br_, bi_, c_) do {                                   \
    _Pragma("unroll")                                                        \
    for (int u = 0; u < 8; ++u) {                                            \
      float nr = fmaf(ar_[u], xr, fmaf(-ai_[u], xi, br_[u]));                \
      float ni = fmaf(ar_[u], xi, fmaf( ai_[u], xr, bi_[u]));                \
      xr = nr; xi = ni;                                                      \
      int l = (c_) * 8 + u;                                                  \
      int phys = bwd ? (LL - 1 - l) : l;                                     \
      int idx = phys * PP + p;                                               \
      outr[idx] = xr; outi[idx] = xi;                                        \
    } } while (0)

  LOADC(a0r, a0i, b0r, b0i, 0);
  for (int c = 0; c < NC; c += 2) {
    LOADC(a1r, a1i, b1r, b1i, c + 1);
    COMPC(a0r, a0i, b0r, b0i, c);
    if (c + 2 < NC) LOADC(a0r, a0i, b0r, b0i, c + 2);
    COMPC(a1r, a1i, b1r, b1i, c + 1);
  }
#undef LOADC
#undef COMPC
}

// ---------------------------------------------------------------- kernel 5
// ys[l][h] = 2*( xs_re@C_re^T - xs_im@C_im^T )[l][h] + D[h]*u[l][h]
// xs = [xf | xb] along K (2P = 1024). 64x64 tile, 4x4/thread.
__global__ __launch_bounds__(256) void gemm2_kernel(
    const float* __restrict__ xfr, const float* __restrict__ xfi,
    const float* __restrict__ xbr, const float* __restrict__ xbi,
    const float* __restrict__ Cr, const float* __restrict__ Ci,
    const float* __restrict__ Dv, const float* __restrict__ U,
    float* __restrict__ Y)
{
  __shared__ float Ars[16][68], Ais[16][68], Crs[16][68], Cis[16][68];
  int t  = threadIdx.x;
  int h0 = blockIdx.x * 64, l0 = blockIdx.y * 64;
  int tx = t & 15, ty = t >> 4;
  int lm = t >> 2, kq = (t & 3) * 4;
  float acc[4][4] = {};

  for (int kc = 0; kc < 64; ++kc) {
    int k0 = kc * 16;
    const float* ar_src; const float* ai_src; int col;
    if (k0 < PP) { ar_src = xfr; ai_src = xfi; col = k0; }
    else         { ar_src = xbr; ai_src = xbi; col = k0 - PP; }
    float4 arv = *(const float4*)&ar_src[(size_t)(l0 + lm) * PP + col + kq];
    float4 aiv = *(const float4*)&ai_src[(size_t)(l0 + lm) * PP + col + kq];
    float4 crv = *(const float4*)&Cr[(size_t)(h0 + lm) * (2 * PP) + k0 + kq];
    float4 civ = *(const float4*)&Ci[(size_t)(h0 + lm) * (2 * PP) + k0 + kq];
    __syncthreads();
    Ars[kq + 0][lm] = arv.x; Ars[kq + 1][lm] = arv.y; Ars[kq + 2][lm] = arv.z; Ars[kq + 3][lm] = arv.w;
    Ais[kq + 0][lm] = aiv.x; Ais[kq + 1][lm] = aiv.y; Ais[kq + 2][lm] = aiv.z; Ais[kq + 3][lm] = aiv.w;
    Crs[kq + 0][lm] = crv.x; Crs[kq + 1][lm] = crv.y; Crs[kq + 2][lm] = crv.z; Crs[kq + 3][lm] = crv.w;
    Cis[kq + 0][lm] = civ.x; Cis[kq + 1][lm] = civ.y; Cis[kq + 2][lm] = civ.z; Cis[kq + 3][lm] = civ.w;
    __syncthreads();
#pragma unroll
    for (int k = 0; k < 16; ++k) {
      float ar[4], ai[4], cr[4], ci[4];
      ld4(&Ars[k][ty * 4], ar);
      ld4(&Ais[k][ty * 4], ai);
      ld4(&Crs[k][tx * 4], cr);
      ld4(&Cis[k][tx * 4], ci);
#pragma unroll
      for (int j = 0; j < 4; ++j)
#pragma unroll
        for (int i = 0; i < 4; ++i) {
          acc[j][i] = fmaf(ar[j],  cr[i], acc[j][i]);
          acc[j][i] = fmaf(-ai[j], ci[i], acc[j][i]);
        }
    }
  }

  float dv4[4];
  ld4(&Dv[h0 + tx * 4], dv4);
#pragma unroll
  for (int j = 0; j < 4; ++j) {
    int row = l0 + ty * 4 + j;
    float uv[4], o[4];
    ld4(&U[(size_t)row * HH + h0 + tx * 4], uv);
#pragma unroll
    for (int i = 0; i < 4; ++i) o[i] = 2.0f * acc[j][i] + dv4[i] * uv[i];
    st4(&Y[(size_t)row * HH + h0 + tx * 4], o);
  }
}

// ---------------------------------------------------------------- launch
extern "C" void kernel_launch(void* const* d_in, const int* in_sizes, int n_in,
                              void* d_out, int out_size, void* d_ws, size_t ws_size,
                              hipStream_t stream)
{
  const float* U   = (const float*)d_in[0];
  const float* Lre = (const float*)d_in[1];
  const float* Lim = (const float*)d_in[2];
  const float* Bre = (const float*)d_in[3];
  const float* Bim = (const float*)d_in[4];
  const float* Cre = (const float*)d_in[5];
  const float* Cim = (const float*)d_in[6];
  const float* Ere = (const float*)d_in[7];
  const float* Eim = (const float*)d_in[8];
  const float* Fre = (const float*)d_in[9];
  const float* Fim = (const float*)d_in[10];
  const float* Dv  = (const float*)d_in[11];
  const float* lst = (const float*)d_in[12];
  const float* Dt  = (const float*)d_in[13];
  float* Y  = (float*)d_out;
  float* ws = (float*)d_ws;

  size_t o = 0;
  float* Lbr = ws + o; o += PP;
  float* Lbi = ws + o; o += PP;
  float* cfr = ws + o; o += PP;
  float* cfi = ws + o; o += PP;
  float* EFr = ws + o; o += (size_t)RR * PP;
  float* EFi = ws + o; o += (size_t)RR * PP;
  float* Bbr = ws + o; o += (size_t)PP * HH;
  float* Bbi = ws + o; o += (size_t)PP * HH;
  float* Aer = ws + o; o += (size_t)LL * PP;
  float* Aei = ws + o; o += (size_t)LL * PP;
  float* Bur = ws + o; o += (size_t)LL * PP;
  float* Bui = ws + o; o += (size_t)LL * PP;
  float* xfr = ws + o; o += (size_t)LL * PP;
  float* xfi = ws + o; o += (size_t)LL * PP;
  float* xbr = ws + o; o += (size_t)LL * PP;
  float* xbi = ws + o; o += (size_t)LL * PP;

  precompute_kernel<<<2, 256, 0, stream>>>(Lre, Lim, lst, Ere, Eim, Fre, Fim,
                                           Lbr, Lbi, cfr, cfi, EFr, EFi);
  bbar_kernel<<<(PP * HH / 4 + 255) / 256, 256, 0, stream>>>(Bre, Bim, cfr, cfi, Bbr, Bbi);
  gemm1_kernel<<<dim3(PP / 64, LL / 64), 256, 0, stream>>>(U, Bbr, Bbi, Dt, EFr, EFi,
                                                           Lbr, Lbi, Bur, Bui, Aer, Aei);
  scan_kernel<<<4, 256, 0, stream>>>(Aer, Aei, Bur, Bui, xfr, xfi, xbr, xbi);
  gemm2_kernel<<<dim3(HH / 64, LL / 64), 256, 0, stream>>>(xfr, xfi, xbr, xbi,
                                                           Cre, Cim, Dv, U, Y);
}

// Round 2
// 457.672 us; speedup vs baseline: 1.6165x; 1.6165x over previous
//
#include <hip/hip_runtime.h>

#define LL 4096
#define HH 1024
#define PP 512
#define RR 16
#define CH 128   // scan chunks
#define CL 32    // steps per chunk (CH*CL == LL)

__device__ __forceinline__ void ld4(const float* p, float v[4]) {
  float4 t = *(const float4*)p;
  v[0] = t.x; v[1] = t.y; v[2] = t.z; v[3] = t.w;
}
__device__ __forceinline__ void st4(float* p, const float v[4]) {
  float4 t; t.x = v[0]; t.y = v[1]; t.z = v[2]; t.w = v[3];
  *(float4*)p = t;
}

// ---------------------------------------------------------------- kernel 1
__global__ void precompute_kernel(const float* __restrict__ Lre, const float* __restrict__ Lim,
                                  const float* __restrict__ lst,
                                  const float* __restrict__ Ere, const float* __restrict__ Eim,
                                  const float* __restrict__ Fre, const float* __restrict__ Fim,
                                  float* __restrict__ Lbr, float* __restrict__ Lbi,
                                  float* __restrict__ cfr, float* __restrict__ cfi,
                                  float* __restrict__ EFr, float* __restrict__ EFi)
{
  int p = blockIdx.x * blockDim.x + threadIdx.x;
  if (p >= PP) return;
  float lre = fminf(Lre[p], -1e-4f);   // clip_eigs
  float lim = Lim[p];
  float st  = expf(lst[p]);
  float er  = expf(lre * st);
  float s, c;
  sincosf(lim * st, &s, &c);
  float lbr = er * c, lbi = er * s;    // Lambda_bar
  Lbr[p] = lbr; Lbi[p] = lbi;
  float den = lre * lre + lim * lim;
  float nr  = lbr - 1.0f;
  cfr[p] = (nr * lre + lbi * lim) / den;
  cfi[p] = (lbi * lre - nr * lim) / den;
  for (int r = 0; r < RR; ++r) {
    float e_r = Ere[p * RR + r], e_i = Eim[p * RR + r];
    float f_r = Fre[r * PP + p], f_i = Fim[r * PP + p];
    EFr[r * PP + p] = e_r * f_r - e_i * f_i;
    EFi[r * PP + p] = e_r * f_i + e_i * f_r;
  }
}

// ---------------------------------------------------------------- kernel 2
__global__ void bbar_kernel(const float* __restrict__ Bre, const float* __restrict__ Bim,
                            const float* __restrict__ cfr, const float* __restrict__ cfi,
                            float* __restrict__ Bbr, float* __restrict__ Bbi)
{
  int i = blockIdx.x * blockDim.x + threadIdx.x;
  int base = i * 4;
  if (base >= PP * HH) return;
  int p = base >> 10;                  // H = 1024
  float cr = cfr[p], ci = cfi[p];
  float4 br = *(const float4*)&Bre[base];
  float4 bi = *(const float4*)&Bim[base];
  float4 orr, oii;
  orr.x = cr * br.x - ci * bi.x;  oii.x = cr * bi.x + ci * br.x;
  orr.y = cr * br.y - ci * bi.y;  oii.y = cr * bi.y + ci * br.y;
  orr.z = cr * br.z - ci * bi.z;  oii.z = cr * bi.z + ci * br.z;
  orr.w = cr * br.w - ci * bi.w;  oii.w = cr * bi.w + ci * br.w;
  *(float4*)&Bbr[base] = orr;
  *(float4*)&Bbi[base] = oii;
}

// ---------------------------------------------------------------- kernel 3
// Bu[l][p] = sum_h u[l][h]*B_bar[p][h]; Lam_el[l][p] = Lambda_bar[p] + (Dt@EF)[l][p]
__global__ __launch_bounds__(256) void gemm1_kernel(
    const float* __restrict__ U,  const float* __restrict__ Bbr, const float* __restrict__ Bbi,
    const float* __restrict__ Dt, const float* __restrict__ EFr, const float* __restrict__ EFi,
    const float* __restrict__ Lbr, const float* __restrict__ Lbi,
    float* __restrict__ Bur, float* __restrict__ Bui,
    float* __restrict__ Ler, float* __restrict__ Lei)
{
  __shared__ float As[16][68], Bsr[16][68], Bsi[16][68];
  int t  = threadIdx.x;
  int p0 = blockIdx.x * 64, l0 = blockIdx.y * 64;
  int tx = t & 15, ty = t >> 4;
  int lm = t >> 2, kq = (t & 3) * 4;
  float accr[4][4] = {}, acci[4][4] = {};

  for (int k0 = 0; k0 < HH; k0 += 16) {
    float4 av  = *(const float4*)&U  [(size_t)(l0 + lm) * HH + k0 + kq];
    float4 brv = *(const float4*)&Bbr[(size_t)(p0 + lm) * HH + k0 + kq];
    float4 biv = *(const float4*)&Bbi[(size_t)(p0 + lm) * HH + k0 + kq];
    __syncthreads();
    As [kq + 0][lm] = av.x;  As [kq + 1][lm] = av.y;  As [kq + 2][lm] = av.z;  As [kq + 3][lm] = av.w;
    Bsr[kq + 0][lm] = brv.x; Bsr[kq + 1][lm] = brv.y; Bsr[kq + 2][lm] = brv.z; Bsr[kq + 3][lm] = brv.w;
    Bsi[kq + 0][lm] = biv.x; Bsi[kq + 1][lm] = biv.y; Bsi[kq + 2][lm] = biv.z; Bsi[kq + 3][lm] = biv.w;
    __syncthreads();
#pragma unroll
    for (int k = 0; k < 16; ++k) {
      float a[4], br[4], bi[4];
      ld4(&As[k][ty * 4], a);
      ld4(&Bsr[k][tx * 4], br);
      ld4(&Bsi[k][tx * 4], bi);
#pragma unroll
      for (int j = 0; j < 4; ++j)
#pragma unroll
        for (int i = 0; i < 4; ++i) {
          accr[j][i] = fmaf(a[j], br[i], accr[j][i]);
          acci[j][i] = fmaf(a[j], bi[i], acci[j][i]);
        }
    }
  }

  // ---- ext = Delta @ EF  (K = 16), reuse LDS
  __syncthreads();
  {
    float4 dv = *(const float4*)&Dt[(size_t)(l0 + lm) * RR + kq];
    As[kq + 0][lm] = dv.x; As[kq + 1][lm] = dv.y; As[kq + 2][lm] = dv.z; As[kq + 3][lm] = dv.w;
    int r = t >> 4, nq = (t & 15) * 4;
    float4 efr = *(const float4*)&EFr[r * PP + p0 + nq];
    float4 efi = *(const float4*)&EFi[r * PP + p0 + nq];
    *(float4*)&Bsr[r][nq] = efr;
    *(float4*)&Bsi[r][nq] = efi;
  }
  __syncthreads();
  float extr[4][4] = {}, exti[4][4] = {};
#pragma unroll
  for (int r = 0; r < 16; ++r) {
    float d[4], er[4], ei[4];
    ld4(&As[r][ty * 4], d);
    ld4(&Bsr[r][tx * 4], er);
    ld4(&Bsi[r][tx * 4], ei);
#pragma unroll
    for (int j = 0; j < 4; ++j)
#pragma unroll
      for (int i = 0; i < 4; ++i) {
        extr[j][i] = fmaf(d[j], er[i], extr[j][i]);
        exti[j][i] = fmaf(d[j], ei[i], exti[j][i]);
      }
  }
  float lbr4[4], lbi4[4];
  ld4(&Lbr[p0 + tx * 4], lbr4);
  ld4(&Lbi[p0 + tx * 4], lbi4);
#pragma unroll
  for (int j = 0; j < 4; ++j) {
    int row = l0 + ty * 4 + j;
    size_t b = (size_t)row * PP + p0 + tx * 4;
    st4(&Bur[b], accr[j]);
    st4(&Bui[b], acci[j]);
    float le_r[4], le_i[4];
#pragma unroll
    for (int i = 0; i < 4; ++i) { le_r[i] = extr[j][i] + lbr4[i]; le_i[i] = exti[j][i] + lbi4[i]; }
    st4(&Ler[b], le_r);
    st4(&Lei[b], le_i);
  }
}

// ---------------------------------------------------------------- scan phase 1
// per-(dir,chunk,p): aggregate (A_prod, b_final) over CL steps.
// layout: idx = (dir*CH + c)*PP + p  == global thread id
__global__ __launch_bounds__(256) void scan_agg_kernel(
    const float* __restrict__ Aer, const float* __restrict__ Aei,
    const float* __restrict__ Bur, const float* __restrict__ Bui,
    float* __restrict__ aggAr, float* __restrict__ aggAi,
    float* __restrict__ aggBr, float* __restrict__ aggBi)
{
  int tid = blockIdx.x * 256 + threadIdx.x;        // 0 .. 2*CH*PP-1
  int p   = tid & (PP - 1);
  int c   = (tid >> 9) & (CH - 1);
  int dir = tid >> 16;
  float Ar = 1.f, Ai = 0.f, br = 0.f, bi = 0.f;
  int base = c * CL;
#pragma unroll
  for (int g = 0; g < CL / 8; ++g) {
    float ar8[8], ai8[8], br8[8], bi8[8];
#pragma unroll
    for (int u = 0; u < 8; ++u) {
      int l = base + g * 8 + u;
      int phys = dir ? (LL - 1 - l) : l;
      int idx = phys * PP + p;
      ar8[u] = Aer[idx]; ai8[u] = Aei[idx];
      br8[u] = Bur[idx]; bi8[u] = Bui[idx];
    }
#pragma unroll
    for (int u = 0; u < 8; ++u) {
      float nAr = ar8[u] * Ar - ai8[u] * Ai;
      float nAi = ar8[u] * Ai + ai8[u] * Ar;
      float nbr = fmaf(ar8[u], br, fmaf(-ai8[u], bi, br8[u]));
      float nbi = fmaf(ar8[u], bi, fmaf( ai8[u], br, bi8[u]));
      Ar = nAr; Ai = nAi; br = nbr; bi = nbi;
    }
  }
  aggAr[tid] = Ar; aggAi[tid] = Ai; aggBr[tid] = br; aggBi[tid] = bi;
}

// ---------------------------------------------------------------- scan phase 2
// serial over chunk aggregates -> carry-in state per chunk (exclusive)
__global__ __launch_bounds__(256) void scan_carry_kernel(
    const float* __restrict__ aggAr, const float* __restrict__ aggAi,
    const float* __restrict__ aggBr, const float* __restrict__ aggBi,
    float* __restrict__ carR, float* __restrict__ carI)
{
  int tid = blockIdx.x * 256 + threadIdx.x;        // 0..1023 : p + dir*PP
  int p   = tid & (PP - 1);
  int dir = tid >> 9;
  float xr = 0.f, xi = 0.f;
  for (int c = 0; c < CH; ++c) {
    int idx = (dir * CH + c) * PP + p;
    carR[idx] = xr; carI[idx] = xi;
    float ar = aggAr[idx], ai = aggAi[idx];
    float br = aggBr[idx], bi = aggBi[idx];
    float nr = fmaf(ar, xr, fmaf(-ai, xi, br));
    float ni = fmaf(ar, xi, fmaf( ai, xr, bi));
    xr = nr; xi = ni;
  }
}

// ---------------------------------------------------------------- scan phase 3
// re-scan each chunk from its carry, writing xs
__global__ __launch_bounds__(256) void scan_apply_kernel(
    const float* __restrict__ Aer, const float* __restrict__ Aei,
    const float* __restrict__ Bur, const float* __restrict__ Bui,
    const float* __restrict__ carR, const float* __restrict__ carI,
    float* __restrict__ xfr, float* __restrict__ xfi,
    float* __restrict__ xbr, float* __restrict__ xbi)
{
  int tid = blockIdx.x * 256 + threadIdx.x;
  int p   = tid & (PP - 1);
  int c   = (tid >> 9) & (CH - 1);
  int dir = tid >> 16;
  float* __restrict__ outr = dir ? xbr : xfr;
  float* __restrict__ outi = dir ? xbi : xfi;
  float xr = carR[tid], xi = carI[tid];
  int base = c * CL;
#pragma unroll
  for (int g = 0; g < CL / 8; ++g) {
    float ar8[8], ai8[8], br8[8], bi8[8];
#pragma unroll
    for (int u = 0; u < 8; ++u) {
      int l = base + g * 8 + u;
      int phys = dir ? (LL - 1 - l) : l;
      int idx = phys * PP + p;
      ar8[u] = Aer[idx]; ai8[u] = Aei[idx];
      br8[u] = Bur[idx]; bi8[u] = Bui[idx];
    }
#pragma unroll
    for (int u = 0; u < 8; ++u) {
      float nr = fmaf(ar8[u], xr, fmaf(-ai8[u], xi, br8[u]));
      float ni = fmaf(ar8[u], xi, fmaf( ai8[u], xr, bi8[u]));
      xr = nr; xi = ni;
      int l = base + g * 8 + u;
      int phys = dir ? (LL - 1 - l) : l;
      int idx = phys * PP + p;
      outr[idx] = xr; outi[idx] = xi;
    }
  }
}

// ---------------------------------------------------------------- kernel 5
__global__ __launch_bounds__(256) void gemm2_kernel(
    const float* __restrict__ xfr, const float* __restrict__ xfi,
    const float* __restrict__ xbr, const float* __restrict__ xbi,
    const float* __restrict__ Cr, const float* __restrict__ Ci,
    const float* __restrict__ Dv, const float* __restrict__ U,
    float* __restrict__ Y)
{
  __shared__ float Ars[16][68], Ais[16][68], Crs[16][68], Cis[16][68];
  int t  = threadIdx.x;
  int h0 = blockIdx.x * 64, l0 = blockIdx.y * 64;
  int tx = t & 15, ty = t >> 4;
  int lm = t >> 2, kq = (t & 3) * 4;
  float acc[4][4] = {};

  for (int kc = 0; kc < 64; ++kc) {
    int k0 = kc * 16;
    const float* ar_src; const float* ai_src; int col;
    if (k0 < PP) { ar_src = xfr; ai_src = xfi; col = k0; }
    else         { ar_src = xbr; ai_src = xbi; col = k0 - PP; }
    float4 arv = *(const float4*)&ar_src[(size_t)(l0 + lm) * PP + col + kq];
    float4 aiv = *(const float4*)&ai_src[(size_t)(l0 + lm) * PP + col + kq];
    float4 crv = *(const float4*)&Cr[(size_t)(h0 + lm) * (2 * PP) + k0 + kq];
    float4 civ = *(const float4*)&Ci[(size_t)(h0 + lm) * (2 * PP) + k0 + kq];
    __syncthreads();
    Ars[kq + 0][lm] = arv.x; Ars[kq + 1][lm] = arv.y; Ars[kq + 2][lm] = arv.z; Ars[kq + 3][lm] = arv.w;
    Ais[kq + 0][lm] = aiv.x; Ais[kq + 1][lm] = aiv.y; Ais[kq + 2][lm] = aiv.z; Ais[kq + 3][lm] = aiv.w;
    Crs[kq + 0][lm] = crv.x; Crs[kq + 1][lm] = crv.y; Crs[kq + 2][lm] = crv.z; Crs[kq + 3][lm] = crv.w;
    Cis[kq + 0][lm] = civ.x; Cis[kq + 1][lm] = civ.y; Cis[kq + 2][lm] = civ.z; Cis[kq + 3][lm] = civ.w;
    __syncthreads();
#pragma unroll
    for (int k = 0; k < 16; ++k) {
      float ar[4], ai[4], cr[4], ci[4];
      ld4(&Ars[k][ty * 4], ar);
      ld4(&Ais[k][ty * 4], ai);
      ld4(&Crs[k][tx * 4], cr);
      ld4(&Cis[k][tx * 4], ci);
#pragma unroll
      for (int j = 0; j < 4; ++j)
#pragma unroll
        for (int i = 0; i < 4; ++i) {
          acc[j][i] = fmaf(ar[j],  cr[i], acc[j][i]);
          acc[j][i] = fmaf(-ai[j], ci[i], acc[j][i]);
        }
    }
  }

  float dv4[4];
  ld4(&Dv[h0 + tx * 4], dv4);
#pragma unroll
  for (int j = 0; j < 4; ++j) {
    int row = l0 + ty * 4 + j;
    float uv[4], o[4];
    ld4(&U[(size_t)row * HH + h0 + tx * 4], uv);
#pragma unroll
    for (int i = 0; i < 4; ++i) o[i] = 2.0f * acc[j][i] + dv4[i] * uv[i];
    st4(&Y[(size_t)row * HH + h0 + tx * 4], o);
  }
}

// ---------------------------------------------------------------- launch
extern "C" void kernel_launch(void* const* d_in, const int* in_sizes, int n_in,
                              void* d_out, int out_size, void* d_ws, size_t ws_size,
                              hipStream_t stream)
{
  const float* U   = (const float*)d_in[0];
  const float* Lre = (const float*)d_in[1];
  const float* Lim = (const float*)d_in[2];
  const float* Bre = (const float*)d_in[3];
  const float* Bim = (const float*)d_in[4];
  const float* Cre = (const float*)d_in[5];
  const float* Cim = (const float*)d_in[6];
  const float* Ere = (const float*)d_in[7];
  const float* Eim = (const float*)d_in[8];
  const float* Fre = (const float*)d_in[9];
  const float* Fim = (const float*)d_in[10];
  const float* Dv  = (const float*)d_in[11];
  const float* lst = (const float*)d_in[12];
  const float* Dt  = (const float*)d_in[13];
  float* Y  = (float*)d_out;
  float* ws = (float*)d_ws;

  size_t o = 0;
  float* Lbr = ws + o; o += PP;
  float* Lbi = ws + o; o += PP;
  float* cfr = ws + o; o += PP;
  float* cfi = ws + o; o += PP;
  float* EFr = ws + o; o += (size_t)RR * PP;
  float* EFi = ws + o; o += (size_t)RR * PP;
  float* Bbr = ws + o; o += (size_t)PP * HH;
  float* Bbi = ws + o; o += (size_t)PP * HH;
  float* Aer = ws + o; o += (size_t)LL * PP;
  float* Aei = ws + o; o += (size_t)LL * PP;
  float* Bur = ws + o; o += (size_t)LL * PP;
  float* Bui = ws + o; o += (size_t)LL * PP;
  float* xfr = ws + o; o += (size_t)LL * PP;
  float* xfi = ws + o; o += (size_t)LL * PP;
  float* xbr = ws + o; o += (size_t)LL * PP;
  float* xbi = ws + o; o += (size_t)LL * PP;

  // scan scratch overlaid on Bbr/Bbi (dead after gemm1; stream-ordered)
  const int NAGG = 2 * CH * PP;                    // 131072
  float* aggAr = Bbr;
  float* aggAi = Bbr + NAGG;
  float* aggBr = Bbr + 2 * (size_t)NAGG;
  float* aggBi = Bbr + 3 * (size_t)NAGG;
  float* carR  = Bbi;
  float* carI  = Bbi + NAGG;

  precompute_kernel<<<2, 256, 0, stream>>>(Lre, Lim, lst, Ere, Eim, Fre, Fim,
                                           Lbr, Lbi, cfr, cfi, EFr, EFi);
  bbar_kernel<<<(PP * HH / 4 + 255) / 256, 256, 0, stream>>>(Bre, Bim, cfr, cfi, Bbr, Bbi);
  gemm1_kernel<<<dim3(PP / 64, LL / 64), 256, 0, stream>>>(U, Bbr, Bbi, Dt, EFr, EFi,
                                                           Lbr, Lbi, Bur, Bui, Aer, Aei);
  scan_agg_kernel<<<(2 * CH * PP) / 256, 256, 0, stream>>>(Aer, Aei, Bur, Bui,
                                                           aggAr, aggAi, aggBr, aggBi);
  scan_carry_kernel<<<4, 256, 0, stream>>>(aggAr, aggAi, aggBr, aggBi, carR, carI);
  scan_apply_kernel<<<(2 * CH * PP) / 256, 256, 0, stream>>>(Aer, Aei, Bur, Bui, carR, carI,
                                                             xfr, xfi, xbr, xbi);
  gemm2_kernel<<<dim3(HH / 64, LL / 64), 256, 0, stream>>>(xfr, xfi, xbr, xbi,
                                                           Cre, Cim, Dv, U, Y);
}